// Round 1
// 192.152 us; speedup vs baseline: 1.0264x; 1.0264x over previous
//
#include <hip/hip_runtime.h>

// PartitionTCA: out[i,j,k] = sum_r v0a[r,i]*v0b[r,j,k]
//                          + sum_r v1a[r,j]*v1b[r,i,k]
//                          + sum_r v2a[r,k]*v2b[r,i,j]
// D0=256 (i), D1=512 (j), D2=256 (k), rank 8, fp32.
//
// R5: kernel is LDS-pipe-bound (reads 25.6us + staging writes 5.4us ~= 33.4us
// measured after subtracting the two 81.8us harness poison fills from dur_us).
//  1. 128-thread blocks, per-thread 4i x 4j x 4k: b128 reads drop 10 -> 7 per
//     f4-output (a1 vectorized too)  => read time 25.6 -> ~18us.
//  2. RS=128 (pad dropped; only 2-way bank aliases remain = free) => every
//     staging dest is linear base+lane*size => global_load_lds DMA for ALL
//     staging (no ds_write issue, no VGPR round-trip). sB2 layout [r][jl][il]
//     so DMA dest is idx-contiguous AND di-reads stay f4-contiguous.
//  3. v2a kept in registers (rv2[8], 32 VGPR) - saves 8 reads/thread + staging.
// Single staging phase before one barrier: acc never live across staging (no
// spill, R4 property). LDS 66.5KB -> 2 blocks/CU, block-level stage/compute
// overlap preserved. Nontemporal stores (write-once output).

typedef float f4 __attribute__((ext_vector_type(4)));

#define RNK 8
#define DD0 256
#define DD1 512
#define DD2 256
#define TI 8
#define TJ 8
#define KC 128
#define RS 128   // row stride in floats (128 = linear, DMA-compatible)

__device__ __forceinline__ void gload16(const float* g, float* l) {
    __builtin_amdgcn_global_load_lds(
        (const __attribute__((address_space(1))) float*)g,
        (__attribute__((address_space(3))) float*)l, 16, 0, 0);
}
__device__ __forceinline__ void gload4(const float* g, float* l) {
    __builtin_amdgcn_global_load_lds(
        (const __attribute__((address_space(1))) float*)g,
        (__attribute__((address_space(3))) float*)l, 4, 0, 0);
}

__global__ __launch_bounds__(128, 1)
void ptca_kernel(const float* __restrict__ v0a, const float* __restrict__ v0b,
                 const float* __restrict__ v1a, const float* __restrict__ v1b,
                 const float* __restrict__ v2a, const float* __restrict__ v2b,
                 float* __restrict__ out)
{
    __shared__ float sA0[RNK * TJ * RS];   // v0b tile [r][jl][k4]  32 KB
    __shared__ float sA1[RNK * TI * RS];   // v1b tile [r][il][k4]  32 KB
    __shared__ float sB2[RNK * TJ * TI];   // v2b tile [r][jl][il]   2 KB
    __shared__ float sa0[RNK * TI];        // v0a [r][il]
    __shared__ float sa1[RNK * TJ];        // v1a [r][jl]

    const int tid = threadIdx.x;
    const int kl  = tid & 31;          // f4 slot along k (k = kc + kl*4 .. +3)
    const int g   = tid >> 5;          // 0..3
    const int it  = g & 1;             // i base = it*4
    const int jt  = g >> 1;            // j base = jt*4
    const int wv  = tid >> 6;          // wave id 0/1

    const int ib = blockIdx.x * TI;
    const int jb = blockIdx.y * TJ;
    const int kc = blockIdx.z * KC;

    // v2a chunk straight to registers (8 KB total array, L2-resident).
    f4 rv2[RNK];
#pragma unroll
    for (int r = 0; r < RNK; ++r)
        rv2[r] = *(const f4*)(v2a + r * DD2 + kc + kl * 4);

    // ---- single async staging phase: global -> LDS DMA ----
#pragma unroll
    for (int q = 0; q < 16; ++q) {         // sA0: 2048 f4, dest idx-linear
        const int idx = tid + q * 128;
        const int kv = idx & 31;
        const int jl = (idx >> 5) & 7;
        const int r  = idx >> 8;
        gload16(v0b + ((size_t)r * DD1 + jb + jl) * DD2 + kc + kv * 4,
                sA0 + (q * 128 + wv * 64) * 4);
    }
#pragma unroll
    for (int q = 0; q < 16; ++q) {         // sA1: 2048 f4
        const int idx = tid + q * 128;
        const int kv = idx & 31;
        const int il = (idx >> 5) & 7;
        const int r  = idx >> 8;
        gload16(v1b + ((size_t)r * DD0 + ib + il) * DD2 + kc + kv * 4,
                sA1 + (q * 128 + wv * 64) * 4);
    }
#pragma unroll
    for (int q = 0; q < 4; ++q) {          // sB2: 512 floats, [r][jl][il] (il inner)
        const int idx = tid + q * 128;
        const int il = idx & 7;
        const int jl = (idx >> 3) & 7;
        const int r  = idx >> 6;
        gload4(v2b + ((size_t)r * DD0 + ib + il) * DD1 + jb + jl,
               sB2 + q * 128 + wv * 64);
    }
    if (wv == 0) {                         // sa0: 64 floats, whole wave 0
        gload4(v0a + (tid >> 3) * DD0 + ib + (tid & 7), sa0);
    } else {                               // sa1: 64 floats, whole wave 1
        const int t = tid - 64;
        gload4(v1a + (t >> 3) * DD1 + jb + (t & 7), sa1);
    }

    __syncthreads();                       // drains vmcnt -> all LDS ready

    // ---- compute: acc live only now ----
    f4 acc[4][4];
#pragma unroll
    for (int di = 0; di < 4; ++di)
#pragma unroll
        for (int dj = 0; dj < 4; ++dj) acc[di][dj] = (f4){0.f, 0.f, 0.f, 0.f};

#pragma unroll
    for (int r = 0; r < RNK; ++r) {
        const f4 a0q = *(const f4*)(sa0 + r * TI + it * 4);     // a0[di]
        const f4 a1q = *(const f4*)(sa1 + r * TJ + jt * 4);     // a1[dj]
        const f4 f2v = rv2[r];
        f4 f1v[4];
#pragma unroll
        for (int di = 0; di < 4; ++di)
            f1v[di] = *(const f4*)(sA1 + (r * TI + it * 4 + di) * RS + kl * 4);

#pragma unroll
        for (int dj = 0; dj < 4; ++dj) {
            const int j = jt * 4 + dj;
            const f4 f0v = *(const f4*)(sA0 + (r * TJ + j) * RS + kl * 4);
            const f4 s2q = *(const f4*)(sB2 + (r * TJ + j) * TI + it * 4); // s2[di]
#pragma unroll
            for (int di = 0; di < 4; ++di)
#pragma unroll
                for (int c = 0; c < 4; ++c)
                    acc[di][dj][c] =
                        __builtin_fmaf(a0q[di], f0v[c],
                        __builtin_fmaf(a1q[dj], f1v[di][c],
                        __builtin_fmaf(s2q[di], f2v[c], acc[di][dj][c])));
        }
    }

    // ---- stores: 512B contiguous segments per row, nontemporal ----
#pragma unroll
    for (int di = 0; di < 4; ++di)
#pragma unroll
        for (int dj = 0; dj < 4; ++dj) {
            const size_t off =
                ((size_t)(ib + it * 4 + di) * DD1 + (jb + jt * 4 + dj)) * DD2
                + kc + kl * 4;
            __builtin_nontemporal_store(acc[di][dj], (f4*)(out + off));
        }
}

extern "C" void kernel_launch(void* const* d_in, const int* in_sizes, int n_in,
                              void* d_out, int out_size, void* d_ws, size_t ws_size,
                              hipStream_t stream) {
    const float* v0a = (const float*)d_in[0];  // [8,256]
    const float* v0b = (const float*)d_in[1];  // [8,512,256]
    const float* v1a = (const float*)d_in[2];  // [8,512]
    const float* v1b = (const float*)d_in[3];  // [8,256,256]
    const float* v2a = (const float*)d_in[4];  // [8,256]
    const float* v2b = (const float*)d_in[5];  // [8,256,512]
    float* out = (float*)d_out;                // [256,512,256]

    dim3 grid(DD0 / TI, DD1 / TJ, DD2 / KC);  // (32,64,2) = 4096 blocks
    ptca_kernel<<<grid, dim3(128), 0, stream>>>(v0a, v0b, v1a, v1b, v2a, v2b, out);
}